// Round 15
// baseline (938.967 us; speedup 1.0000x reference)
//
#include <hip/hip_runtime.h>

#define N_NODES 50000
#define N_EDGES 400000
#define NG 64
#define NT 2
#define EPS 1e-5f
#define NB_N ((N_NODES + 255) / 256)   /* 196 */
#define NB_E ((N_EDGES + 255) / 256)   /* 1563 */
#define NB_A ((N_NODES + 31) / 32)     /* 1563: 8 lanes/node, 32 nodes/block */

// ---------------------------------------------------------------------------
// Moment index mapping: flat t in [0,44): t<8 -> S[t]; t>=8 -> upper-tri (i,j)
// ---------------------------------------------------------------------------
constexpr int mom_i(int t) {
    int tt = t - 8; int i = 0;
    while (tt >= 8 - i) { tt -= 8 - i; ++i; }
    return i;
}
constexpr int mom_j(int t) {
    int tt = t - 8; int i = 0;
    while (tt >= 8 - i) { tt -= 8 - i; ++i; }
    return i + tt;
}

template<int IDX>
__device__ __forceinline__ float mom_term(const float* v) {
    if constexpr (IDX >= 44) return 0.f;
    else if constexpr (IDX < 8) return v[IDX];
    else return v[mom_i(IDX)] * v[mom_j(IDX)];
}

template<int BASE>
__device__ __forceinline__ void mom_add16(const float* v, float* acc) {
    acc[0]  += mom_term<BASE + 0>(v);
    acc[1]  += mom_term<BASE + 1>(v);
    acc[2]  += mom_term<BASE + 2>(v);
    acc[3]  += mom_term<BASE + 3>(v);
    acc[4]  += mom_term<BASE + 4>(v);
    acc[5]  += mom_term<BASE + 5>(v);
    acc[6]  += mom_term<BASE + 6>(v);
    acc[7]  += mom_term<BASE + 7>(v);
    acc[8]  += mom_term<BASE + 8>(v);
    acc[9]  += mom_term<BASE + 9>(v);
    acc[10] += mom_term<BASE + 10>(v);
    acc[11] += mom_term<BASE + 11>(v);
    acc[12] += mom_term<BASE + 12>(v);
    acc[13] += mom_term<BASE + 13>(v);
    acc[14] += mom_term<BASE + 14>(v);
    acc[15] += mom_term<BASE + 15>(v);
}

template<int BASE>
__device__ __forceinline__ void mom_loop(
    const float* __restrict__ ea, const int* __restrict__ dst,
    int* __restrict__ deg, float* acc)
{
    const int stride = gridDim.x * 256;
    for (int e = blockIdx.x * 256 + threadIdx.x; e < N_EDGES; e += stride) {
        const float4 a4 = ((const float4*)ea)[e * 2];
        const float4 b4 = ((const float4*)ea)[e * 2 + 1];
        const float v[8] = {a4.x,a4.y,a4.z,a4.w, b4.x,b4.y,b4.z,b4.w};
        if constexpr (BASE == 0) atomicAdd(deg + dst[e], 1);
        mom_add16<BASE>(v, acc);
    }
}

// ---------------------------------------------------------------------------
// K1: edge-attr moments, 3 chunks of 16; chunk 0 also builds in-degree.
// ---------------------------------------------------------------------------
__global__ __launch_bounds__(256) void k_moments(
    const float* __restrict__ ea, const int* __restrict__ dst,
    float* __restrict__ mom, int* __restrict__ deg)
{
    const int c = blockIdx.y;
    float acc[16];
    #pragma unroll
    for (int u = 0; u < 16; ++u) acc[u] = 0.f;
    switch (c) {
        case 0: mom_loop<0 >(ea, dst, deg, acc); break;
        case 1: mom_loop<16>(ea, dst, deg, acc); break;
        default: mom_loop<32>(ea, dst, deg, acc); break;
    }
    __shared__ float red[4][16];
    const int lane = threadIdx.x & 63, wv = threadIdx.x >> 6;
    #pragma unroll
    for (int u = 0; u < 16; ++u) {
        float s = acc[u];
        #pragma unroll
        for (int o = 32; o; o >>= 1) s += __shfl_down(s, o);
        if (lane == 0) red[wv][u] = s;
    }
    __syncthreads();
    if (threadIdx.x < 16) {
        const int idx = c * 16 + threadIdx.x;
        if (idx < 44) {
            const float s = red[0][threadIdx.x] + red[1][threadIdx.x]
                          + red[2][threadIdx.x] + red[3][threadIdx.x];
            atomicAdd(mom + idx, s);
        }
    }
}

// ---------------------------------------------------------------------------
// K2: block scan of deg -> loc/bsum; also degree histogram (clamped 128).
// ---------------------------------------------------------------------------
__global__ __launch_bounds__(256) void k_scan1(
    const int* __restrict__ deg, int* __restrict__ loc, int* __restrict__ bsum,
    int* __restrict__ hist)
{
    __shared__ int s[256];
    __shared__ int shist[128];
    const int t = threadIdx.x;
    const int n = blockIdx.x * 256 + t;
    const int v = (n < N_NODES) ? deg[n] : 0;
    if (t < 128) shist[t] = 0;
    s[t] = v;
    __syncthreads();
    #pragma unroll
    for (int d = 1; d < 256; d <<= 1) {
        const int a = (t >= d) ? s[t - d] : 0;
        __syncthreads();
        s[t] += a;
        __syncthreads();
    }
    if (n < N_NODES) {
        loc[n] = s[t] - v;
        atomicAdd(&shist[min(v, 127)], 1);
    }
    if (t == 255) bsum[blockIdx.x] = s[t];
    __syncthreads();
    if (t < 128 && shist[t]) atomicAdd(hist + t, shist[t]);
}

// ---------------------------------------------------------------------------
// K3 ("singles"): scan bsum; analytic BN finalize; graph starts; degree-bucket
// suffix scan. ss per conv: [scale32 | shift32].
// ---------------------------------------------------------------------------
__global__ __launch_bounds__(256) void k_singles(
    int* __restrict__ bsum, const float* __restrict__ mom,
    const float* __restrict__ W1a, const float* __restrict__ b1a,
    const float* __restrict__ ga,  const float* __restrict__ bea,
    const float* __restrict__ W1b, const float* __restrict__ b1b,
    const float* __restrict__ gb,  const float* __restrict__ beb,
    float* __restrict__ ss, const int* __restrict__ batch,
    int* __restrict__ start, const int* __restrict__ hist,
    int* __restrict__ cursor)
{
    __shared__ int s[256];
    const int t = threadIdx.x;
    const int v = (t < NB_N) ? bsum[t] : 0;
    s[t] = v;
    __syncthreads();
    #pragma unroll
    for (int d = 1; d < 256; d <<= 1) {
        const int a = (t >= d) ? s[t - d] : 0;
        __syncthreads();
        s[t] += a;
        __syncthreads();
    }
    if (t < NB_N) bsum[t] = s[t] - v;

    if (t < 64) {
        const int m = t >> 5, k = t & 31;
        const float* W1 = m ? W1b : W1a;
        const float b   = (m ? b1b : b1a)[k];
        const float g   = (m ? gb  : ga)[k];
        const float be  = (m ? beb : bea)[k];
        float w[8];
        #pragma unroll
        for (int j = 0; j < 8; ++j) w[j] = W1[j * 32 + k];
        float Sw = 0.f;
        #pragma unroll
        for (int j = 0; j < 8; ++j) Sw += mom[j] * w[j];
        float q = 0.f;
        int idx = 8;
        #pragma unroll
        for (int i = 0; i < 8; ++i)
            #pragma unroll
            for (int j = i; j < 8; ++j) {
                const float Mv = mom[idx++];
                q += Mv * w[i] * w[j] * (i == j ? 1.f : 2.f);
            }
        const float invE  = 1.0f / (float)N_EDGES;
        const float sump  = Sw + (float)N_EDGES * b;
        const float sumpp = q + 2.f * b * Sw + (float)N_EDGES * b * b;
        const float mean  = sump * invE;
        const float var   = fmaxf(sumpp * invE - mean * mean, 0.f);
        const float sc    = g * rsqrtf(var + EPS);
        ss[m * 64 + k]      = sc;
        ss[m * 64 + 32 + k] = be - mean * sc;
    }
    if (t <= NG) {
        int lo = 0, hi = N_NODES;
        while (lo < hi) {
            const int mid = (lo + hi) >> 1;
            if (batch[mid] < t) lo = mid + 1; else hi = mid;
        }
        start[t] = lo;
    }
    if (t == 0) {
        int acc = 0;
        for (int d = 127; d >= 0; --d) { cursor[d] = acc; acc += hist[d]; }
    }
}

// ---------------------------------------------------------------------------
// K4: finalize offsets + degree-descending permutation (two-level reservation).
// ---------------------------------------------------------------------------
__global__ __launch_bounds__(256) void k_scan3(
    const int* __restrict__ loc, const int* __restrict__ bsum,
    const int* __restrict__ deg, int* __restrict__ off, int* __restrict__ cur,
    int* __restrict__ cursor, int* __restrict__ perm)
{
    __shared__ int scnt[128];
    __shared__ int sbase[128];
    const int t = threadIdx.x;
    const int n = blockIdx.x * 256 + t;
    if (t < 128) scnt[t] = 0;
    __syncthreads();
    int b = 0, rk = 0;
    if (n < N_NODES) {
        const int o = loc[n] + bsum[n >> 8];
        off[n] = o; cur[n] = o;
        if (n == 0) off[N_NODES] = N_EDGES;
        b  = min(deg[n], 127);
        rk = atomicAdd(&scnt[b], 1);
    }
    __syncthreads();
    if (t < 128 && scnt[t]) sbase[t] = atomicAdd(cursor + t, scnt[t]);
    __syncthreads();
    if (n < N_NODES) perm[sbase[b] + rk] = n;
}

// scatter edges into dst-sorted order: src id + edge-attr row
__global__ __launch_bounds__(256) void k_pos(
    const int* __restrict__ src, const int* __restrict__ dst,
    const float* __restrict__ ea, int* __restrict__ cur,
    int* __restrict__ src_s, float4* __restrict__ ea_s)
{
    const int e = blockIdx.x * 256 + threadIdx.x;
    if (e < N_EDGES) {
        const float4 a4 = ((const float4*)ea)[e * 2];
        const float4 b4 = ((const float4*)ea)[e * 2 + 1];
        const int p = atomicAdd(cur + dst[e], 1);
        src_s[p] = src[e];
        ea_s[p * 2]     = a4;
        ea_s[p * 2 + 1] = b4;
    }
}

// ---------------------------------------------------------------------------
// K5: rank-1 aggregation + fused node-pre epilogue.
// LDS = sW2q ONLY (exactly 32768 B -> 5 blocks/CU); root/b2/bias columns are
// read from global (L2-hot float2, once per block) in the epilogue; lacc is
// aliased into sW2q after projection (guarded by __syncthreads).
// __launch_bounds__(256,5) caps VGPR at 102 for 5 waves/SIMD.
// ---------------------------------------------------------------------------
__global__ __launch_bounds__(256, 5) void k_agg(
    const float* __restrict__ x, const float4* __restrict__ ea_s,
    const int* __restrict__ src_s, const int* __restrict__ off,
    const int* __restrict__ perm,
    const float* __restrict__ W1, const float* __restrict__ W2,
    const float* __restrict__ ss, const float* __restrict__ root,
    const float* __restrict__ b2, const float* __restrict__ bias,
    float* __restrict__ pre_out, float* __restrict__ bnstats)
{
    __shared__ float4 sW2q[2048];   // 32KB exactly, phys idx = f ^ ((f>>8)&7)
    const int tid = threadIdx.x;
    #pragma unroll
    for (int i = 0; i < 8; ++i) {
        const int f = tid + 256 * i;
        sW2q[f ^ ((f >> 8) & 7)] = ((const float4*)W2)[f];
    }
    __syncthreads();

    const int c  = tid & 7;
    const int g  = blockIdx.x * 32 + (tid >> 3);
    const bool valid = (g < N_NODES);
    const int n  = perm[valid ? g : (N_NODES - 1)];

    float w1r[32];                  // W1[j][4c+kk]
    #pragma unroll
    for (int j = 0; j < 8; ++j)
        #pragma unroll
        for (int kk = 0; kk < 4; ++kk)
            w1r[j * 4 + kk] = W1[j * 32 + c * 4 + kk];
    float scr[4], shr[4];
    #pragma unroll
    for (int kk = 0; kk < 4; ++kk) {
        scr[kk] = ss[c * 4 + kk];
        shr[kk] = ss[32 + c * 4 + kk];
    }

    const int o0 = off[n], o1 = off[n + 1];
    const int len = o1 - o0;
    float T[64];
    #pragma unroll
    for (int j = 0; j < 64; ++j) T[j] = 0.f;
    float xs0 = 0.f, xs1 = 0.f;

    // decoupled 2-stage pipeline (round-10 exact)
    float4 ca = make_float4(0,0,0,0), cb = ca;
    float4 cx0 = ca, cx1 = ca, cx2 = ca, cx3 = ca;
    float2 cxs = make_float2(0.f, 0.f);
    float4 pa = ca, pb = ca;
    int    snn = 0;
    if (len > 0) {
        const int s0 = src_s[o0];
        ca = ea_s[(size_t)o0 * 2];
        cb = ea_s[(size_t)o0 * 2 + 1];
        const float4* xp = (const float4*)(x + (size_t)s0 * 16);
        cx0 = xp[0]; cx1 = xp[1]; cx2 = xp[2]; cx3 = xp[3];
        cxs = *(const float2*)(x + (size_t)s0 * 16 + (c << 1));
        pa = ca; pb = cb;
        if (len > 1) {
            snn = src_s[o0 + 1];
            pa = ea_s[(size_t)(o0 + 1) * 2];
            pb = ea_s[(size_t)(o0 + 1) * 2 + 1];
        }
    }
    for (int r = 0; r < len; ++r) {
        float4 nx0 = cx0, nx1 = cx1, nx2 = cx2, nx3 = cx3;
        float2 nxs = cxs;
        float4 qa = pa, qb = pb;
        int sn2 = snn;
        if (r + 1 < len) {
            const float4* xp = (const float4*)(x + (size_t)snn * 16);
            nx0 = xp[0]; nx1 = xp[1]; nx2 = xp[2]; nx3 = xp[3];
            nxs = *(const float2*)(x + (size_t)snn * 16 + (c << 1));
        }
        if (r + 2 < len) {
            sn2 = src_s[o0 + r + 2];
            qa = ea_s[(size_t)(o0 + r + 2) * 2];
            qb = ea_s[(size_t)(o0 + r + 2) * 2 + 1];
        }
        const float ein[8] = {ca.x,ca.y,ca.z,ca.w, cb.x,cb.y,cb.z,cb.w};
        float h[4];
        #pragma unroll
        for (int kk = 0; kk < 4; ++kk) {
            float p = 0.f;
            #pragma unroll
            for (int j = 0; j < 8; ++j) p += ein[j] * w1r[j * 4 + kk];
            h[kk] = fmaxf(p * scr[kk] + shr[kk], 0.f);
        }
        const float xv[16] = {cx0.x,cx0.y,cx0.z,cx0.w, cx1.x,cx1.y,cx1.z,cx1.w,
                              cx2.x,cx2.y,cx2.z,cx2.w, cx3.x,cx3.y,cx3.z,cx3.w};
        #pragma unroll
        for (int kk = 0; kk < 4; ++kk) {
            const float hk = h[kk];
            #pragma unroll
            for (int i = 0; i < 16; ++i) T[kk * 16 + i] += hk * xv[i];
        }
        xs0 += cxs.x;
        xs1 += cxs.y;
        ca = pa; cb = pb;
        cx0 = nx0; cx1 = nx1; cx2 = nx2; cx3 = nx3;
        cxs = nxs;
        pa = qa; pb = qb; snn = sn2;
    }

    // projection (round-10 exact: XOR-swizzled, broadcast across groups)
    float agg[16];
    #pragma unroll
    for (int o = 0; o < 16; ++o) agg[o] = 0.f;
    #pragma unroll
    for (int kk = 0; kk < 4; ++kk) {
        const int fbase = (c * 4 + kk) * 64;
        #pragma unroll
        for (int i = 0; i < 16; ++i) {
            const float tv = T[kk * 16 + i];
            const int f0 = fbase + i * 4;
            const float4 w0 = sW2q[(f0 + 0) ^ c];
            const float4 w1 = sW2q[(f0 + 1) ^ c];
            const float4 w2 = sW2q[(f0 + 2) ^ c];
            const float4 w3 = sW2q[(f0 + 3) ^ c];
            agg[0]+=tv*w0.x; agg[1]+=tv*w0.y; agg[2]+=tv*w0.z; agg[3]+=tv*w0.w;
            agg[4]+=tv*w1.x; agg[5]+=tv*w1.y; agg[6]+=tv*w1.z; agg[7]+=tv*w1.w;
            agg[8]+=tv*w2.x; agg[9]+=tv*w2.y; agg[10]+=tv*w2.z; agg[11]+=tv*w2.w;
            agg[12]+=tv*w3.x; agg[13]+=tv*w3.y; agg[14]+=tv*w3.z; agg[15]+=tv*w3.w;
        }
    }
    #pragma unroll
    for (int m = 1; m < 8; m <<= 1) {
        #pragma unroll
        for (int o = 0; o < 16; ++o) agg[o] += __shfl_xor(agg[o], m);
    }

    // ---------------- fused node-pre epilogue (params from global) --------
    const int gb = (tid & 63) & 56;      // wave-local 8-lane group base
    float xsum[16];
    #pragma unroll
    for (int i = 0; i < 8; ++i) {
        xsum[2 * i]     = __shfl(xs0, gb + i);
        xsum[2 * i + 1] = __shfl(xs1, gb + i);
    }
    const int c0 = c * 2, c1 = c * 2 + 1;
    float p0 = agg[c * 2], p1 = agg[c * 2 + 1];
    #pragma unroll
    for (int i = 0; i < 16; ++i) {
        const float2 bv = *(const float2*)(b2 + i * 16 + c0);
        p0 += xsum[i] * bv.x;
        p1 += xsum[i] * bv.y;
    }
    const float invd = 1.0f / (float)max(len, 1);
    const float2 biasv = *(const float2*)(bias + c0);
    p0 = p0 * invd + biasv.x;
    p1 = p1 * invd + biasv.y;
    const float4* xrp = (const float4*)(x + (size_t)n * 16);
    const float4 r0 = xrp[0], r1 = xrp[1], r2 = xrp[2], r3 = xrp[3];
    const float xn[16] = {r0.x,r0.y,r0.z,r0.w, r1.x,r1.y,r1.z,r1.w,
                          r2.x,r2.y,r2.z,r2.w, r3.x,r3.y,r3.z,r3.w};
    #pragma unroll
    for (int i = 0; i < 16; ++i) {
        const float2 rv = *(const float2*)(root + i * 16 + c0);
        p0 += xn[i] * rv.x;
        p1 += xn[i] * rv.y;
    }
    if (valid) {
        ((float2*)(pre_out + (size_t)n * 16))[c] = make_float2(p0, p1);
    } else { p0 = 0.f; p1 = 0.f; }
    // BN partial stats: reduce across the 8 node-groups in the wave
    float q0 = p0 * p0, q1 = p1 * p1;
    #pragma unroll
    for (int m = 8; m < 64; m <<= 1) {
        p0 += __shfl_xor(p0, m); p1 += __shfl_xor(p1, m);
        q0 += __shfl_xor(q0, m); q1 += __shfl_xor(q1, m);
    }
    // alias lacc into sW2q (all projection reads are done after this barrier)
    __syncthreads();
    float* lacc = (float*)sW2q;
    if (tid < 32) lacc[tid] = 0.f;
    __syncthreads();
    if ((tid & 63) < 8) {
        atomicAdd(&lacc[c0], p0);       atomicAdd(&lacc[c1], p1);
        atomicAdd(&lacc[16 + c0], q0);  atomicAdd(&lacc[16 + c1], q1);
    }
    __syncthreads();
    if (tid < 32) atomicAdd(bnstats + tid, lacc[tid]);
}

// ---------------------------------------------------------------------------
// K6: apply node BN + ReLU (conv1): stats are 32 finalized floats
// ---------------------------------------------------------------------------
__global__ __launch_bounds__(256) void k_node_bn(
    const float* __restrict__ pre, const float* __restrict__ bnstats,
    const float* __restrict__ gam, const float* __restrict__ bet,
    float* __restrict__ hout)
{
    __shared__ float sscale[16], sshift[16];
    const int tid = threadIdx.x;
    if (tid < 16) {
        const float mean = bnstats[tid] * (1.0f / N_NODES);
        const float var  = fmaxf(bnstats[16 + tid] * (1.0f / N_NODES) - mean * mean, 0.f);
        const float rs   = rsqrtf(var + EPS);
        const float sc   = gam[tid] * rs;
        sscale[tid] = sc;
        sshift[tid] = bet[tid] - mean * sc;
    }
    __syncthreads();
    const int n = blockIdx.x * 256 + tid;
    if (n >= N_NODES) return;
    const float4* pp = (const float4*)(pre + (size_t)n * 16);
    const float4 p0=pp[0],p1=pp[1],p2=pp[2],p3=pp[3];
    const float pv[16] = {p0.x,p0.y,p0.z,p0.w, p1.x,p1.y,p1.z,p1.w,
                          p2.x,p2.y,p2.z,p2.w, p3.x,p3.y,p3.z,p3.w};
    float h[16];
    #pragma unroll
    for (int o = 0; o < 16; ++o) h[o] = fmaxf(pv[o] * sscale[o] + sshift[o], 0.f);
    float4* hp = (float4*)(hout + (size_t)n * 16);
    hp[0] = make_float4(h[0],h[1],h[2],h[3]);
    hp[1] = make_float4(h[4],h[5],h[6],h[7]);
    hp[2] = make_float4(h[8],h[9],h[10],h[11]);
    hp[3] = make_float4(h[12],h[13],h[14],h[15]);
}

// ---------------------------------------------------------------------------
// K7: per-graph mean pool with BN2+ReLU fused (stats are finalized floats)
// ---------------------------------------------------------------------------
__global__ __launch_bounds__(256) void k_pool_bn(
    const float* __restrict__ pre, const float* __restrict__ bnstats,
    const float* __restrict__ gam, const float* __restrict__ bet,
    const int* __restrict__ start, float* __restrict__ pool)
{
    __shared__ float sscale[16], sshift[16];
    __shared__ float lds[16][16];
    const int tid = threadIdx.x;
    if (tid < 16) {
        const float mean = bnstats[tid] * (1.0f / N_NODES);
        const float var  = fmaxf(bnstats[16 + tid] * (1.0f / N_NODES) - mean * mean, 0.f);
        const float rs   = rsqrtf(var + EPS);
        const float sc   = gam[tid] * rs;
        sscale[tid] = sc;
        sshift[tid] = bet[tid] - mean * sc;
    }
    __syncthreads();
    const int g = blockIdx.x;
    const int c = tid & 15, rg = tid >> 4;
    const int s = start[g], e = start[g + 1];
    const float sc = sscale[c], sh = sshift[c];
    float acc = 0.f;
    for (int r = s + rg; r < e; r += 16)
        acc += fmaxf(pre[(size_t)r * 16 + c] * sc + sh, 0.f);
    lds[rg][c] = acc;
    __syncthreads();
    if (tid < 16) {
        float sum = 0.f;
        #pragma unroll
        for (int i = 0; i < 16; ++i) sum += lds[i][tid];
        const float inv = 1.0f / (float)max(e - s, 1);
        pool[g * 16 + tid] = sum * inv;
    }
}

// ---------------------------------------------------------------------------
// K8: head MLP
// ---------------------------------------------------------------------------
__global__ __launch_bounds__(64) void k_head(
    const float* __restrict__ pool,
    const float* __restrict__ fc1W, const float* __restrict__ fc1b,
    const float* __restrict__ fc2W, const float* __restrict__ fc2b,
    float* __restrict__ out)
{
    const int g = threadIdx.x;
    if (g >= NG) return;
    float p[16];
    #pragma unroll
    for (int o = 0; o < 16; ++o) p[o] = pool[g * 16 + o];
    float z[16];
    #pragma unroll
    for (int j = 0; j < 16; ++j) {
        float a = fc1b[j];
        #pragma unroll
        for (int o = 0; o < 16; ++o) a += p[o] * fc1W[o * 16 + j];
        z[j] = fmaxf(a, 0.f);
    }
    #pragma unroll
    for (int t = 0; t < NT; ++t) {
        float a = fc2b[t];
        #pragma unroll
        for (int j = 0; j < 16; ++j) a += z[j] * fc2W[j * 2 + t];
        out[g * 2 + t] = a;
    }
}

// ---------------------------------------------------------------------------
extern "C" void kernel_launch(void* const* d_in, const int* in_sizes, int n_in,
                              void* d_out, int out_size, void* d_ws, size_t ws_size,
                              hipStream_t stream)
{
    const float* x    = (const float*)d_in[0];
    const float* ea   = (const float*)d_in[1];
    const float* e1W1 = (const float*)d_in[2];  const float* e1b1 = (const float*)d_in[3];
    const float* e1g  = (const float*)d_in[4];  const float* e1be = (const float*)d_in[5];
    const float* e1W2 = (const float*)d_in[6];  const float* e1b2 = (const float*)d_in[7];
    const float* c1r  = (const float*)d_in[8];  const float* c1b  = (const float*)d_in[9];
    const float* e2W1 = (const float*)d_in[10]; const float* e2b1 = (const float*)d_in[11];
    const float* e2g  = (const float*)d_in[12]; const float* e2be = (const float*)d_in[13];
    const float* e2W2 = (const float*)d_in[14]; const float* e2b2 = (const float*)d_in[15];
    const float* c2r  = (const float*)d_in[16]; const float* c2b  = (const float*)d_in[17];
    const float* bn1g = (const float*)d_in[18]; const float* bn1b = (const float*)d_in[19];
    const float* bn2g = (const float*)d_in[20]; const float* bn2b = (const float*)d_in[21];
    const float* fc1W = (const float*)d_in[22]; const float* fc1b = (const float*)d_in[23];
    const float* fc2W = (const float*)d_in[24]; const float* fc2b = (const float*)d_in[25];
    const int* eidx   = (const int*)d_in[26];
    const int* batch  = (const int*)d_in[27];
    const int* src = eidx;
    const int* dst = eidx + N_EDGES;

    float* ws      = (float*)d_ws;
    float* mom     = ws;                      // 64 (44 used)
    float* bnstats = ws + 64;                 // 64 (32 per conv, zeroed)
    float* ss      = ws + 128;                // 128
    int* hist_i    = (int*)(ws + 256);        // 128 (zeroed)
    int* cursor_i  = (int*)(ws + 384);        // 128
    int* deg_i   = (int*)(ws + 512);          // N (zeroed)
    int* loc_i   = deg_i + N_NODES;           // N
    int* cur_i   = loc_i + N_NODES;           // N
    int* bsum_i  = cur_i + N_NODES;           // 256
    int* start_i = bsum_i + 256;              // 65 (pad 72)
    int* off_i   = start_i + 72;              // N+1 (pad N+8)
    int* perm_i  = off_i + N_NODES + 8;       // N
    int* src_s   = perm_i + N_NODES;          // E
    const size_t fo = 512 + 256 + 72 + 8 + 5 * (size_t)N_NODES + (size_t)N_EDGES;
    float* ea_s  = ws + fo;                        // E*8 (16B aligned)
    float* pre1  = ea_s + (size_t)N_EDGES * 8;     // N*16 (reused as pre2)
    float* h1n   = pre1 + (size_t)N_NODES * 16;    // N*16
    float* pool  = h1n + (size_t)N_NODES * 16;     // NG*16

    // zero: mom+bnstats+ss+hist+cursor (512 floats) + deg (N ints), contiguous
    hipMemsetAsync(d_ws, 0, (size_t)(512 + N_NODES) * sizeof(float), stream);

    k_moments<<<dim3(512, 3), 256, 0, stream>>>(ea, dst, mom, deg_i);
    k_scan1<<<NB_N, 256, 0, stream>>>(deg_i, loc_i, bsum_i, hist_i);
    k_singles<<<1, 256, 0, stream>>>(bsum_i, mom, e1W1, e1b1, e1g, e1be,
                                     e2W1, e2b1, e2g, e2be, ss, batch, start_i,
                                     hist_i, cursor_i);
    k_scan3<<<NB_N, 256, 0, stream>>>(loc_i, bsum_i, deg_i, off_i, cur_i,
                                      cursor_i, perm_i);
    k_pos<<<NB_E, 256, 0, stream>>>(src, dst, ea, cur_i, src_s, (float4*)ea_s);

    k_agg<<<NB_A, 256, 0, stream>>>(x, (const float4*)ea_s, src_s, off_i, perm_i,
                                    e1W1, e1W2, ss, c1r, e1b2, c1b, pre1, bnstats);
    k_node_bn<<<NB_N, 256, 0, stream>>>(pre1, bnstats, bn1g, bn1b, h1n);

    k_agg<<<NB_A, 256, 0, stream>>>(h1n, (const float4*)ea_s, src_s, off_i, perm_i,
                                    e2W1, e2W2, ss + 64, c2r, e2b2, c2b, pre1,
                                    bnstats + 32);
    k_pool_bn<<<NG, 256, 0, stream>>>(pre1, bnstats + 32, bn2g, bn2b, start_i, pool);
    k_head<<<1, 64, 0, stream>>>(pool, fc1W, fc1b, fc2W, fc2b, (float*)d_out);
}

// Round 16
// 214.503 us; speedup vs baseline: 4.3774x; 4.3774x over previous
//
#include <hip/hip_runtime.h>

#define N_NODES 50000
#define N_EDGES 400000
#define NG 64
#define NT 2
#define EPS 1e-5f
#define NB_N ((N_NODES + 255) / 256)   /* 196 */
#define NB_E ((N_EDGES + 255) / 256)   /* 1563 */
#define NB_A ((N_NODES + 31) / 32)     /* 1563: 8 lanes/node, 32 nodes/block */

// ---------------------------------------------------------------------------
// Moment index mapping: flat t in [0,44): t<8 -> S[t]; t>=8 -> upper-tri (i,j)
// ---------------------------------------------------------------------------
constexpr int mom_i(int t) {
    int tt = t - 8; int i = 0;
    while (tt >= 8 - i) { tt -= 8 - i; ++i; }
    return i;
}
constexpr int mom_j(int t) {
    int tt = t - 8; int i = 0;
    while (tt >= 8 - i) { tt -= 8 - i; ++i; }
    return i + tt;
}

template<int IDX>
__device__ __forceinline__ float mom_term(const float* v) {
    if constexpr (IDX >= 44) return 0.f;
    else if constexpr (IDX < 8) return v[IDX];
    else return v[mom_i(IDX)] * v[mom_j(IDX)];
}

template<int BASE>
__device__ __forceinline__ void mom_add16(const float* v, float* acc) {
    acc[0]  += mom_term<BASE + 0>(v);
    acc[1]  += mom_term<BASE + 1>(v);
    acc[2]  += mom_term<BASE + 2>(v);
    acc[3]  += mom_term<BASE + 3>(v);
    acc[4]  += mom_term<BASE + 4>(v);
    acc[5]  += mom_term<BASE + 5>(v);
    acc[6]  += mom_term<BASE + 6>(v);
    acc[7]  += mom_term<BASE + 7>(v);
    acc[8]  += mom_term<BASE + 8>(v);
    acc[9]  += mom_term<BASE + 9>(v);
    acc[10] += mom_term<BASE + 10>(v);
    acc[11] += mom_term<BASE + 11>(v);
    acc[12] += mom_term<BASE + 12>(v);
    acc[13] += mom_term<BASE + 13>(v);
    acc[14] += mom_term<BASE + 14>(v);
    acc[15] += mom_term<BASE + 15>(v);
}

template<int BASE>
__device__ __forceinline__ void mom_loop(
    const float* __restrict__ ea, const int* __restrict__ dst,
    int* __restrict__ deg, float* acc)
{
    const int stride = gridDim.x * 256;
    for (int e = blockIdx.x * 256 + threadIdx.x; e < N_EDGES; e += stride) {
        const float4 a4 = ((const float4*)ea)[e * 2];
        const float4 b4 = ((const float4*)ea)[e * 2 + 1];
        const float v[8] = {a4.x,a4.y,a4.z,a4.w, b4.x,b4.y,b4.z,b4.w};
        if constexpr (BASE == 0) atomicAdd(deg + dst[e], 1);
        mom_add16<BASE>(v, acc);
    }
}

// ---------------------------------------------------------------------------
// K1: edge-attr moments, 3 chunks of 16; chunk 0 also builds in-degree.
// ---------------------------------------------------------------------------
__global__ __launch_bounds__(256) void k_moments(
    const float* __restrict__ ea, const int* __restrict__ dst,
    float* __restrict__ mom, int* __restrict__ deg)
{
    const int c = blockIdx.y;
    float acc[16];
    #pragma unroll
    for (int u = 0; u < 16; ++u) acc[u] = 0.f;
    switch (c) {
        case 0: mom_loop<0 >(ea, dst, deg, acc); break;
        case 1: mom_loop<16>(ea, dst, deg, acc); break;
        default: mom_loop<32>(ea, dst, deg, acc); break;
    }
    __shared__ float red[4][16];
    const int lane = threadIdx.x & 63, wv = threadIdx.x >> 6;
    #pragma unroll
    for (int u = 0; u < 16; ++u) {
        float s = acc[u];
        #pragma unroll
        for (int o = 32; o; o >>= 1) s += __shfl_down(s, o);
        if (lane == 0) red[wv][u] = s;
    }
    __syncthreads();
    if (threadIdx.x < 16) {
        const int idx = c * 16 + threadIdx.x;
        if (idx < 44) {
            const float s = red[0][threadIdx.x] + red[1][threadIdx.x]
                          + red[2][threadIdx.x] + red[3][threadIdx.x];
            atomicAdd(mom + idx, s);
        }
    }
}

// ---------------------------------------------------------------------------
// K2: block scan of deg -> loc/bsum; also degree histogram (clamped 128).
// ---------------------------------------------------------------------------
__global__ __launch_bounds__(256) void k_scan1(
    const int* __restrict__ deg, int* __restrict__ loc, int* __restrict__ bsum,
    int* __restrict__ hist)
{
    __shared__ int s[256];
    __shared__ int shist[128];
    const int t = threadIdx.x;
    const int n = blockIdx.x * 256 + t;
    const int v = (n < N_NODES) ? deg[n] : 0;
    if (t < 128) shist[t] = 0;
    s[t] = v;
    __syncthreads();
    #pragma unroll
    for (int d = 1; d < 256; d <<= 1) {
        const int a = (t >= d) ? s[t - d] : 0;
        __syncthreads();
        s[t] += a;
        __syncthreads();
    }
    if (n < N_NODES) {
        loc[n] = s[t] - v;
        atomicAdd(&shist[min(v, 127)], 1);
    }
    if (t == 255) bsum[blockIdx.x] = s[t];
    __syncthreads();
    if (t < 128 && shist[t]) atomicAdd(hist + t, shist[t]);
}

// ---------------------------------------------------------------------------
// K3 ("singles"): scan bsum; analytic BN finalize; graph starts; degree-bucket
// suffix scan. ss per conv: [scale32 | shift32].
// ---------------------------------------------------------------------------
__global__ __launch_bounds__(256) void k_singles(
    int* __restrict__ bsum, const float* __restrict__ mom,
    const float* __restrict__ W1a, const float* __restrict__ b1a,
    const float* __restrict__ ga,  const float* __restrict__ bea,
    const float* __restrict__ W1b, const float* __restrict__ b1b,
    const float* __restrict__ gb,  const float* __restrict__ beb,
    float* __restrict__ ss, const int* __restrict__ batch,
    int* __restrict__ start, const int* __restrict__ hist,
    int* __restrict__ cursor)
{
    __shared__ int s[256];
    const int t = threadIdx.x;
    const int v = (t < NB_N) ? bsum[t] : 0;
    s[t] = v;
    __syncthreads();
    #pragma unroll
    for (int d = 1; d < 256; d <<= 1) {
        const int a = (t >= d) ? s[t - d] : 0;
        __syncthreads();
        s[t] += a;
        __syncthreads();
    }
    if (t < NB_N) bsum[t] = s[t] - v;

    if (t < 64) {
        const int m = t >> 5, k = t & 31;
        const float* W1 = m ? W1b : W1a;
        const float b   = (m ? b1b : b1a)[k];
        const float g   = (m ? gb  : ga)[k];
        const float be  = (m ? beb : bea)[k];
        float w[8];
        #pragma unroll
        for (int j = 0; j < 8; ++j) w[j] = W1[j * 32 + k];
        float Sw = 0.f;
        #pragma unroll
        for (int j = 0; j < 8; ++j) Sw += mom[j] * w[j];
        float q = 0.f;
        int idx = 8;
        #pragma unroll
        for (int i = 0; i < 8; ++i)
            #pragma unroll
            for (int j = i; j < 8; ++j) {
                const float Mv = mom[idx++];
                q += Mv * w[i] * w[j] * (i == j ? 1.f : 2.f);
            }
        const float invE  = 1.0f / (float)N_EDGES;
        const float sump  = Sw + (float)N_EDGES * b;
        const float sumpp = q + 2.f * b * Sw + (float)N_EDGES * b * b;
        const float mean  = sump * invE;
        const float var   = fmaxf(sumpp * invE - mean * mean, 0.f);
        const float sc    = g * rsqrtf(var + EPS);
        ss[m * 64 + k]      = sc;
        ss[m * 64 + 32 + k] = be - mean * sc;
    }
    if (t <= NG) {
        int lo = 0, hi = N_NODES;
        while (lo < hi) {
            const int mid = (lo + hi) >> 1;
            if (batch[mid] < t) lo = mid + 1; else hi = mid;
        }
        start[t] = lo;
    }
    if (t == 0) {
        int acc = 0;
        for (int d = 127; d >= 0; --d) { cursor[d] = acc; acc += hist[d]; }
    }
}

// ---------------------------------------------------------------------------
// K4: finalize offsets + degree-descending permutation (two-level reservation).
// ---------------------------------------------------------------------------
__global__ __launch_bounds__(256) void k_scan3(
    const int* __restrict__ loc, const int* __restrict__ bsum,
    const int* __restrict__ deg, int* __restrict__ off, int* __restrict__ cur,
    int* __restrict__ cursor, int* __restrict__ perm)
{
    __shared__ int scnt[128];
    __shared__ int sbase[128];
    const int t = threadIdx.x;
    const int n = blockIdx.x * 256 + t;
    if (t < 128) scnt[t] = 0;
    __syncthreads();
    int b = 0, rk = 0;
    if (n < N_NODES) {
        const int o = loc[n] + bsum[n >> 8];
        off[n] = o; cur[n] = o;
        if (n == 0) off[N_NODES] = N_EDGES;
        b  = min(deg[n], 127);
        rk = atomicAdd(&scnt[b], 1);
    }
    __syncthreads();
    if (t < 128 && scnt[t]) sbase[t] = atomicAdd(cursor + t, scnt[t]);
    __syncthreads();
    if (n < N_NODES) perm[sbase[b] + rk] = n;
}

// scatter edges into dst-sorted order: src id + edge-attr row
__global__ __launch_bounds__(256) void k_pos(
    const int* __restrict__ src, const int* __restrict__ dst,
    const float* __restrict__ ea, int* __restrict__ cur,
    int* __restrict__ src_s, float4* __restrict__ ea_s)
{
    const int e = blockIdx.x * 256 + threadIdx.x;
    if (e < N_EDGES) {
        const float4 a4 = ((const float4*)ea)[e * 2];
        const float4 b4 = ((const float4*)ea)[e * 2 + 1];
        const int p = atomicAdd(cur + dst[e], 1);
        src_s[p] = src[e];
        ea_s[p * 2]     = a4;
        ea_s[p * 2 + 1] = b4;
    }
}

// ---------------------------------------------------------------------------
// K5: rank-1 aggregation + FUSED node-pre epilogue (round-14 EXACT: 104 VGPR,
// 35328 LDS, 4 blocks/CU -- do not touch; caps below 104 spill T[64]).
// ---------------------------------------------------------------------------
__global__ __launch_bounds__(256) void k_agg(
    const float* __restrict__ x, const float4* __restrict__ ea_s,
    const int* __restrict__ src_s, const int* __restrict__ off,
    const int* __restrict__ perm,
    const float* __restrict__ W1, const float* __restrict__ W2,
    const float* __restrict__ ss, const float* __restrict__ root,
    const float* __restrict__ b2, const float* __restrict__ bias,
    float* __restrict__ pre_out, float* __restrict__ bnstats)
{
    __shared__ float4 sW2q[2048];   // 32KB, phys idx = f ^ ((f>>8)&7)
    __shared__ float sroot[256], sb2[256], sbias[16], lacc[32];
    const int tid = threadIdx.x;
    #pragma unroll
    for (int i = 0; i < 8; ++i) {
        const int f = tid + 256 * i;
        sW2q[f ^ ((f >> 8) & 7)] = ((const float4*)W2)[f];
    }
    if (tid < 64) {
        ((float4*)sroot)[tid] = ((const float4*)root)[tid];
        ((float4*)sb2)[tid]   = ((const float4*)b2)[tid];
    }
    if (tid < 16) sbias[tid] = bias[tid];
    if (tid < 32) lacc[tid] = 0.f;
    __syncthreads();

    const int c  = tid & 7;
    const int g  = blockIdx.x * 32 + (tid >> 3);
    const bool valid = (g < N_NODES);
    const int n  = perm[valid ? g : (N_NODES - 1)];

    float w1r[32];                  // W1[j][4c+kk]
    #pragma unroll
    for (int j = 0; j < 8; ++j)
        #pragma unroll
        for (int kk = 0; kk < 4; ++kk)
            w1r[j * 4 + kk] = W1[j * 32 + c * 4 + kk];
    float scr[4], shr[4];
    #pragma unroll
    for (int kk = 0; kk < 4; ++kk) {
        scr[kk] = ss[c * 4 + kk];
        shr[kk] = ss[32 + c * 4 + kk];
    }

    const int o0 = off[n], o1 = off[n + 1];
    const int len = o1 - o0;
    float T[64];
    #pragma unroll
    for (int j = 0; j < 64; ++j) T[j] = 0.f;
    float xs0 = 0.f, xs1 = 0.f;

    // decoupled 2-stage pipeline (round-10 exact)
    float4 ca = make_float4(0,0,0,0), cb = ca;
    float4 cx0 = ca, cx1 = ca, cx2 = ca, cx3 = ca;
    float2 cxs = make_float2(0.f, 0.f);
    float4 pa = ca, pb = ca;
    int    snn = 0;
    if (len > 0) {
        const int s0 = src_s[o0];
        ca = ea_s[(size_t)o0 * 2];
        cb = ea_s[(size_t)o0 * 2 + 1];
        const float4* xp = (const float4*)(x + (size_t)s0 * 16);
        cx0 = xp[0]; cx1 = xp[1]; cx2 = xp[2]; cx3 = xp[3];
        cxs = *(const float2*)(x + (size_t)s0 * 16 + (c << 1));
        pa = ca; pb = cb;
        if (len > 1) {
            snn = src_s[o0 + 1];
            pa = ea_s[(size_t)(o0 + 1) * 2];
            pb = ea_s[(size_t)(o0 + 1) * 2 + 1];
        }
    }
    for (int r = 0; r < len; ++r) {
        float4 nx0 = cx0, nx1 = cx1, nx2 = cx2, nx3 = cx3;
        float2 nxs = cxs;
        float4 qa = pa, qb = pb;
        int sn2 = snn;
        if (r + 1 < len) {
            const float4* xp = (const float4*)(x + (size_t)snn * 16);
            nx0 = xp[0]; nx1 = xp[1]; nx2 = xp[2]; nx3 = xp[3];
            nxs = *(const float2*)(x + (size_t)snn * 16 + (c << 1));
        }
        if (r + 2 < len) {
            sn2 = src_s[o0 + r + 2];
            qa = ea_s[(size_t)(o0 + r + 2) * 2];
            qb = ea_s[(size_t)(o0 + r + 2) * 2 + 1];
        }
        const float ein[8] = {ca.x,ca.y,ca.z,ca.w, cb.x,cb.y,cb.z,cb.w};
        float h[4];
        #pragma unroll
        for (int kk = 0; kk < 4; ++kk) {
            float p = 0.f;
            #pragma unroll
            for (int j = 0; j < 8; ++j) p += ein[j] * w1r[j * 4 + kk];
            h[kk] = fmaxf(p * scr[kk] + shr[kk], 0.f);
        }
        const float xv[16] = {cx0.x,cx0.y,cx0.z,cx0.w, cx1.x,cx1.y,cx1.z,cx1.w,
                              cx2.x,cx2.y,cx2.z,cx2.w, cx3.x,cx3.y,cx3.z,cx3.w};
        #pragma unroll
        for (int kk = 0; kk < 4; ++kk) {
            const float hk = h[kk];
            #pragma unroll
            for (int i = 0; i < 16; ++i) T[kk * 16 + i] += hk * xv[i];
        }
        xs0 += cxs.x;
        xs1 += cxs.y;
        ca = pa; cb = pb;
        cx0 = nx0; cx1 = nx1; cx2 = nx2; cx3 = nx3;
        cxs = nxs;
        pa = qa; pb = qb; snn = sn2;
    }

    // projection (round-10 exact: XOR-swizzled, broadcast across groups)
    float agg[16];
    #pragma unroll
    for (int o = 0; o < 16; ++o) agg[o] = 0.f;
    #pragma unroll
    for (int kk = 0; kk < 4; ++kk) {
        const int fbase = (c * 4 + kk) * 64;
        #pragma unroll
        for (int i = 0; i < 16; ++i) {
            const float tv = T[kk * 16 + i];
            const int f0 = fbase + i * 4;
            const float4 w0 = sW2q[(f0 + 0) ^ c];
            const float4 w1 = sW2q[(f0 + 1) ^ c];
            const float4 w2 = sW2q[(f0 + 2) ^ c];
            const float4 w3 = sW2q[(f0 + 3) ^ c];
            agg[0]+=tv*w0.x; agg[1]+=tv*w0.y; agg[2]+=tv*w0.z; agg[3]+=tv*w0.w;
            agg[4]+=tv*w1.x; agg[5]+=tv*w1.y; agg[6]+=tv*w1.z; agg[7]+=tv*w1.w;
            agg[8]+=tv*w2.x; agg[9]+=tv*w2.y; agg[10]+=tv*w2.z; agg[11]+=tv*w2.w;
            agg[12]+=tv*w3.x; agg[13]+=tv*w3.y; agg[14]+=tv*w3.z; agg[15]+=tv*w3.w;
        }
    }
    #pragma unroll
    for (int m = 1; m < 8; m <<= 1) {
        #pragma unroll
        for (int o = 0; o < 16; ++o) agg[o] += __shfl_xor(agg[o], m);
    }

    // ---------------- fused node-pre epilogue (round-13, verified) --------
    const int gb = (tid & 63) & 56;      // wave-local 8-lane group base
    float xsum[16];
    #pragma unroll
    for (int i = 0; i < 8; ++i) {
        xsum[2 * i]     = __shfl(xs0, gb + i);
        xsum[2 * i + 1] = __shfl(xs1, gb + i);
    }
    const int c0 = c * 2, c1 = c * 2 + 1;
    float p0 = agg[c * 2], p1 = agg[c * 2 + 1];
    #pragma unroll
    for (int i = 0; i < 16; ++i) {
        p0 += xsum[i] * sb2[i * 16 + c0];
        p1 += xsum[i] * sb2[i * 16 + c1];
    }
    const float invd = 1.0f / (float)max(len, 1);
    p0 = p0 * invd + sbias[c0];
    p1 = p1 * invd + sbias[c1];
    const float4* xrp = (const float4*)(x + (size_t)n * 16);
    const float4 r0 = xrp[0], r1 = xrp[1], r2 = xrp[2], r3 = xrp[3];
    const float xn[16] = {r0.x,r0.y,r0.z,r0.w, r1.x,r1.y,r1.z,r1.w,
                          r2.x,r2.y,r2.z,r2.w, r3.x,r3.y,r3.z,r3.w};
    #pragma unroll
    for (int i = 0; i < 16; ++i) {
        p0 += xn[i] * sroot[i * 16 + c0];
        p1 += xn[i] * sroot[i * 16 + c1];
    }
    if (valid) {
        ((float2*)(pre_out + (size_t)n * 16))[c] = make_float2(p0, p1);
    } else { p0 = 0.f; p1 = 0.f; }
    // BN partial stats: reduce across the 8 node-groups in the wave
    float q0 = p0 * p0, q1 = p1 * p1;
    #pragma unroll
    for (int m = 8; m < 64; m <<= 1) {
        p0 += __shfl_xor(p0, m); p1 += __shfl_xor(p1, m);
        q0 += __shfl_xor(q0, m); q1 += __shfl_xor(q1, m);
    }
    if ((tid & 63) < 8) {
        atomicAdd(&lacc[c0], p0);       atomicAdd(&lacc[c1], p1);
        atomicAdd(&lacc[16 + c0], q0);  atomicAdd(&lacc[16 + c1], q1);
    }
    __syncthreads();
    if (tid < 32) atomicAdd(bnstats + tid, lacc[tid]);
}

// ---------------------------------------------------------------------------
// K6: apply node BN + ReLU (conv1): stats are 32 finalized floats
// ---------------------------------------------------------------------------
__global__ __launch_bounds__(256) void k_node_bn(
    const float* __restrict__ pre, const float* __restrict__ bnstats,
    const float* __restrict__ gam, const float* __restrict__ bet,
    float* __restrict__ hout)
{
    __shared__ float sscale[16], sshift[16];
    const int tid = threadIdx.x;
    if (tid < 16) {
        const float mean = bnstats[tid] * (1.0f / N_NODES);
        const float var  = fmaxf(bnstats[16 + tid] * (1.0f / N_NODES) - mean * mean, 0.f);
        const float rs   = rsqrtf(var + EPS);
        const float sc   = gam[tid] * rs;
        sscale[tid] = sc;
        sshift[tid] = bet[tid] - mean * sc;
    }
    __syncthreads();
    const int n = blockIdx.x * 256 + tid;
    if (n >= N_NODES) return;
    const float4* pp = (const float4*)(pre + (size_t)n * 16);
    const float4 p0=pp[0],p1=pp[1],p2=pp[2],p3=pp[3];
    const float pv[16] = {p0.x,p0.y,p0.z,p0.w, p1.x,p1.y,p1.z,p1.w,
                          p2.x,p2.y,p2.z,p2.w, p3.x,p3.y,p3.z,p3.w};
    float h[16];
    #pragma unroll
    for (int o = 0; o < 16; ++o) h[o] = fmaxf(pv[o] * sscale[o] + sshift[o], 0.f);
    float4* hp = (float4*)(hout + (size_t)n * 16);
    hp[0] = make_float4(h[0],h[1],h[2],h[3]);
    hp[1] = make_float4(h[4],h[5],h[6],h[7]);
    hp[2] = make_float4(h[8],h[9],h[10],h[11]);
    hp[3] = make_float4(h[12],h[13],h[14],h[15]);
}

// ---------------------------------------------------------------------------
// K7: per-graph mean pool with BN2+ReLU fused AND head MLP fused (one block
// per graph; head needs only this graph's pooled vector).
// ---------------------------------------------------------------------------
__global__ __launch_bounds__(256) void k_pool_bn(
    const float* __restrict__ pre, const float* __restrict__ bnstats,
    const float* __restrict__ gam, const float* __restrict__ bet,
    const int* __restrict__ start,
    const float* __restrict__ fc1W, const float* __restrict__ fc1b,
    const float* __restrict__ fc2W, const float* __restrict__ fc2b,
    float* __restrict__ out)
{
    __shared__ float sscale[16], sshift[16];
    __shared__ float lds[16][16];
    __shared__ float sp[16], sz[16];
    const int tid = threadIdx.x;
    if (tid < 16) {
        const float mean = bnstats[tid] * (1.0f / N_NODES);
        const float var  = fmaxf(bnstats[16 + tid] * (1.0f / N_NODES) - mean * mean, 0.f);
        const float rs   = rsqrtf(var + EPS);
        const float sc   = gam[tid] * rs;
        sscale[tid] = sc;
        sshift[tid] = bet[tid] - mean * sc;
    }
    __syncthreads();
    const int g = blockIdx.x;
    const int c = tid & 15, rg = tid >> 4;
    const int s = start[g], e = start[g + 1];
    const float sc = sscale[c], sh = sshift[c];
    float acc = 0.f;
    for (int r = s + rg; r < e; r += 16)
        acc += fmaxf(pre[(size_t)r * 16 + c] * sc + sh, 0.f);
    lds[rg][c] = acc;
    __syncthreads();
    if (tid < 16) {
        float sum = 0.f;
        #pragma unroll
        for (int i = 0; i < 16; ++i) sum += lds[i][tid];
        sp[tid] = sum / (float)max(e - s, 1);
    }
    __syncthreads();
    if (tid < 16) {
        float a = fc1b[tid];
        #pragma unroll
        for (int o = 0; o < 16; ++o) a += sp[o] * fc1W[o * 16 + tid];
        sz[tid] = fmaxf(a, 0.f);
    }
    __syncthreads();
    if (tid < NT) {
        float a = fc2b[tid];
        #pragma unroll
        for (int j = 0; j < 16; ++j) a += sz[j] * fc2W[j * 2 + tid];
        out[g * 2 + tid] = a;
    }
}

// ---------------------------------------------------------------------------
extern "C" void kernel_launch(void* const* d_in, const int* in_sizes, int n_in,
                              void* d_out, int out_size, void* d_ws, size_t ws_size,
                              hipStream_t stream)
{
    const float* x    = (const float*)d_in[0];
    const float* ea   = (const float*)d_in[1];
    const float* e1W1 = (const float*)d_in[2];  const float* e1b1 = (const float*)d_in[3];
    const float* e1g  = (const float*)d_in[4];  const float* e1be = (const float*)d_in[5];
    const float* e1W2 = (const float*)d_in[6];  const float* e1b2 = (const float*)d_in[7];
    const float* c1r  = (const float*)d_in[8];  const float* c1b  = (const float*)d_in[9];
    const float* e2W1 = (const float*)d_in[10]; const float* e2b1 = (const float*)d_in[11];
    const float* e2g  = (const float*)d_in[12]; const float* e2be = (const float*)d_in[13];
    const float* e2W2 = (const float*)d_in[14]; const float* e2b2 = (const float*)d_in[15];
    const float* c2r  = (const float*)d_in[16]; const float* c2b  = (const float*)d_in[17];
    const float* bn1g = (const float*)d_in[18]; const float* bn1b = (const float*)d_in[19];
    const float* bn2g = (const float*)d_in[20]; const float* bn2b = (const float*)d_in[21];
    const float* fc1W = (const float*)d_in[22]; const float* fc1b = (const float*)d_in[23];
    const float* fc2W = (const float*)d_in[24]; const float* fc2b = (const float*)d_in[25];
    const int* eidx   = (const int*)d_in[26];
    const int* batch  = (const int*)d_in[27];
    const int* src = eidx;
    const int* dst = eidx + N_EDGES;

    float* ws      = (float*)d_ws;
    float* mom     = ws;                      // 64 (44 used)
    float* bnstats = ws + 64;                 // 64 (32 per conv, zeroed)
    float* ss      = ws + 128;                // 128
    int* hist_i    = (int*)(ws + 256);        // 128 (zeroed)
    int* cursor_i  = (int*)(ws + 384);        // 128
    int* deg_i   = (int*)(ws + 512);          // N (zeroed)
    int* loc_i   = deg_i + N_NODES;           // N
    int* cur_i   = loc_i + N_NODES;           // N
    int* bsum_i  = cur_i + N_NODES;           // 256
    int* start_i = bsum_i + 256;              // 65 (pad 72)
    int* off_i   = start_i + 72;              // N+1 (pad N+8)
    int* perm_i  = off_i + N_NODES + 8;       // N
    int* src_s   = perm_i + N_NODES;          // E
    const size_t fo = 512 + 256 + 72 + 8 + 5 * (size_t)N_NODES + (size_t)N_EDGES;
    float* ea_s  = ws + fo;                        // E*8 (16B aligned)
    float* pre1  = ea_s + (size_t)N_EDGES * 8;     // N*16 (reused as pre2)
    float* h1n   = pre1 + (size_t)N_NODES * 16;    // N*16

    // zero: mom+bnstats+ss+hist+cursor (512 floats) + deg (N ints), contiguous
    hipMemsetAsync(d_ws, 0, (size_t)(512 + N_NODES) * sizeof(float), stream);

    k_moments<<<dim3(512, 3), 256, 0, stream>>>(ea, dst, mom, deg_i);
    k_scan1<<<NB_N, 256, 0, stream>>>(deg_i, loc_i, bsum_i, hist_i);
    k_singles<<<1, 256, 0, stream>>>(bsum_i, mom, e1W1, e1b1, e1g, e1be,
                                     e2W1, e2b1, e2g, e2be, ss, batch, start_i,
                                     hist_i, cursor_i);
    k_scan3<<<NB_N, 256, 0, stream>>>(loc_i, bsum_i, deg_i, off_i, cur_i,
                                      cursor_i, perm_i);
    k_pos<<<NB_E, 256, 0, stream>>>(src, dst, ea, cur_i, src_s, (float4*)ea_s);

    k_agg<<<NB_A, 256, 0, stream>>>(x, (const float4*)ea_s, src_s, off_i, perm_i,
                                    e1W1, e1W2, ss, c1r, e1b2, c1b, pre1, bnstats);
    k_node_bn<<<NB_N, 256, 0, stream>>>(pre1, bnstats, bn1g, bn1b, h1n);

    k_agg<<<NB_A, 256, 0, stream>>>(h1n, (const float4*)ea_s, src_s, off_i, perm_i,
                                    e2W1, e2W2, ss + 64, c2r, e2b2, c2b, pre1,
                                    bnstats + 32);
    k_pool_bn<<<NG, 256, 0, stream>>>(pre1, bnstats + 32, bn2g, bn2b, start_i,
                                      fc1W, fc1b, fc2W, fc2b, (float*)d_out);
}

// Round 17
// 211.006 us; speedup vs baseline: 4.4500x; 1.0166x over previous
//
#include <hip/hip_runtime.h>

#define N_NODES 50000
#define N_EDGES 400000
#define NG 64
#define NT 2
#define EPS 1e-5f
#define NB_N ((N_NODES + 255) / 256)   /* 196 */
#define NB_E ((N_EDGES + 255) / 256)   /* 1563 */
#define NB_A ((N_NODES + 31) / 32)     /* 1563: 8 lanes/node, 32 nodes/block */

// ---------------------------------------------------------------------------
// Moment index mapping: flat t in [0,44): t<8 -> S[t]; t>=8 -> upper-tri (i,j)
// ---------------------------------------------------------------------------
constexpr int mom_i(int t) {
    int tt = t - 8; int i = 0;
    while (tt >= 8 - i) { tt -= 8 - i; ++i; }
    return i;
}
constexpr int mom_j(int t) {
    int tt = t - 8; int i = 0;
    while (tt >= 8 - i) { tt -= 8 - i; ++i; }
    return i + tt;
}

template<int IDX>
__device__ __forceinline__ float mom_term(const float* v) {
    if constexpr (IDX >= 44) return 0.f;
    else if constexpr (IDX < 8) return v[IDX];
    else return v[mom_i(IDX)] * v[mom_j(IDX)];
}

template<int BASE>
__device__ __forceinline__ void mom_add16(const float* v, float* acc) {
    acc[0]  += mom_term<BASE + 0>(v);
    acc[1]  += mom_term<BASE + 1>(v);
    acc[2]  += mom_term<BASE + 2>(v);
    acc[3]  += mom_term<BASE + 3>(v);
    acc[4]  += mom_term<BASE + 4>(v);
    acc[5]  += mom_term<BASE + 5>(v);
    acc[6]  += mom_term<BASE + 6>(v);
    acc[7]  += mom_term<BASE + 7>(v);
    acc[8]  += mom_term<BASE + 8>(v);
    acc[9]  += mom_term<BASE + 9>(v);
    acc[10] += mom_term<BASE + 10>(v);
    acc[11] += mom_term<BASE + 11>(v);
    acc[12] += mom_term<BASE + 12>(v);
    acc[13] += mom_term<BASE + 13>(v);
    acc[14] += mom_term<BASE + 14>(v);
    acc[15] += mom_term<BASE + 15>(v);
}

// ---------------------------------------------------------------------------
// K1: edge-attr moments, SINGLE pass (48 static register accumulators, no
// runtime-indexed arrays); also builds per-node in-degree. 512 blocks keeps
// per-address atomic depth identical to the old 3-pass version while reading
// ea once instead of 3x.
// ---------------------------------------------------------------------------
__global__ __launch_bounds__(256) void k_moments(
    const float* __restrict__ ea, const int* __restrict__ dst,
    float* __restrict__ mom, int* __restrict__ deg)
{
    float acc[48];
    #pragma unroll
    for (int u = 0; u < 48; ++u) acc[u] = 0.f;
    const int stride = gridDim.x * 256;
    for (int e = blockIdx.x * 256 + threadIdx.x; e < N_EDGES; e += stride) {
        const float4 a4 = ((const float4*)ea)[e * 2];
        const float4 b4 = ((const float4*)ea)[e * 2 + 1];
        const float v[8] = {a4.x,a4.y,a4.z,a4.w, b4.x,b4.y,b4.z,b4.w};
        atomicAdd(deg + dst[e], 1);
        mom_add16<0 >(v, acc);
        mom_add16<16>(v, acc + 16);
        mom_add16<32>(v, acc + 32);
    }
    __shared__ float red[4][48];
    const int lane = threadIdx.x & 63, wv = threadIdx.x >> 6;
    #pragma unroll
    for (int u = 0; u < 48; ++u) {
        float s = acc[u];
        #pragma unroll
        for (int o = 32; o; o >>= 1) s += __shfl_down(s, o);
        if (lane == 0) red[wv][u] = s;
    }
    __syncthreads();
    if (threadIdx.x < 44) {
        const float s = red[0][threadIdx.x] + red[1][threadIdx.x]
                      + red[2][threadIdx.x] + red[3][threadIdx.x];
        atomicAdd(mom + threadIdx.x, s);
    }
}

// ---------------------------------------------------------------------------
// K2: block scan of deg -> loc/bsum; also degree histogram (clamped 128).
// ---------------------------------------------------------------------------
__global__ __launch_bounds__(256) void k_scan1(
    const int* __restrict__ deg, int* __restrict__ loc, int* __restrict__ bsum,
    int* __restrict__ hist)
{
    __shared__ int s[256];
    __shared__ int shist[128];
    const int t = threadIdx.x;
    const int n = blockIdx.x * 256 + t;
    const int v = (n < N_NODES) ? deg[n] : 0;
    if (t < 128) shist[t] = 0;
    s[t] = v;
    __syncthreads();
    #pragma unroll
    for (int d = 1; d < 256; d <<= 1) {
        const int a = (t >= d) ? s[t - d] : 0;
        __syncthreads();
        s[t] += a;
        __syncthreads();
    }
    if (n < N_NODES) {
        loc[n] = s[t] - v;
        atomicAdd(&shist[min(v, 127)], 1);
    }
    if (t == 255) bsum[blockIdx.x] = s[t];
    __syncthreads();
    if (t < 128 && shist[t]) atomicAdd(hist + t, shist[t]);
}

// ---------------------------------------------------------------------------
// K3 ("singles"): scan bsum; analytic BN finalize; graph starts; degree-bucket
// suffix scan. ss per conv: [scale32 | shift32].
// ---------------------------------------------------------------------------
__global__ __launch_bounds__(256) void k_singles(
    int* __restrict__ bsum, const float* __restrict__ mom,
    const float* __restrict__ W1a, const float* __restrict__ b1a,
    const float* __restrict__ ga,  const float* __restrict__ bea,
    const float* __restrict__ W1b, const float* __restrict__ b1b,
    const float* __restrict__ gb,  const float* __restrict__ beb,
    float* __restrict__ ss, const int* __restrict__ batch,
    int* __restrict__ start, const int* __restrict__ hist,
    int* __restrict__ cursor)
{
    __shared__ int s[256];
    const int t = threadIdx.x;
    const int v = (t < NB_N) ? bsum[t] : 0;
    s[t] = v;
    __syncthreads();
    #pragma unroll
    for (int d = 1; d < 256; d <<= 1) {
        const int a = (t >= d) ? s[t - d] : 0;
        __syncthreads();
        s[t] += a;
        __syncthreads();
    }
    if (t < NB_N) bsum[t] = s[t] - v;

    if (t < 64) {
        const int m = t >> 5, k = t & 31;
        const float* W1 = m ? W1b : W1a;
        const float b   = (m ? b1b : b1a)[k];
        const float g   = (m ? gb  : ga)[k];
        const float be  = (m ? beb : bea)[k];
        float w[8];
        #pragma unroll
        for (int j = 0; j < 8; ++j) w[j] = W1[j * 32 + k];
        float Sw = 0.f;
        #pragma unroll
        for (int j = 0; j < 8; ++j) Sw += mom[j] * w[j];
        float q = 0.f;
        int idx = 8;
        #pragma unroll
        for (int i = 0; i < 8; ++i)
            #pragma unroll
            for (int j = i; j < 8; ++j) {
                const float Mv = mom[idx++];
                q += Mv * w[i] * w[j] * (i == j ? 1.f : 2.f);
            }
        const float invE  = 1.0f / (float)N_EDGES;
        const float sump  = Sw + (float)N_EDGES * b;
        const float sumpp = q + 2.f * b * Sw + (float)N_EDGES * b * b;
        const float mean  = sump * invE;
        const float var   = fmaxf(sumpp * invE - mean * mean, 0.f);
        const float sc    = g * rsqrtf(var + EPS);
        ss[m * 64 + k]      = sc;
        ss[m * 64 + 32 + k] = be - mean * sc;
    }
    if (t <= NG) {
        int lo = 0, hi = N_NODES;
        while (lo < hi) {
            const int mid = (lo + hi) >> 1;
            if (batch[mid] < t) lo = mid + 1; else hi = mid;
        }
        start[t] = lo;
    }
    if (t == 0) {
        int acc = 0;
        for (int d = 127; d >= 0; --d) { cursor[d] = acc; acc += hist[d]; }
    }
}

// ---------------------------------------------------------------------------
// K4: finalize offsets + degree-descending permutation (two-level reservation).
// ---------------------------------------------------------------------------
__global__ __launch_bounds__(256) void k_scan3(
    const int* __restrict__ loc, const int* __restrict__ bsum,
    const int* __restrict__ deg, int* __restrict__ off, int* __restrict__ cur,
    int* __restrict__ cursor, int* __restrict__ perm)
{
    __shared__ int scnt[128];
    __shared__ int sbase[128];
    const int t = threadIdx.x;
    const int n = blockIdx.x * 256 + t;
    if (t < 128) scnt[t] = 0;
    __syncthreads();
    int b = 0, rk = 0;
    if (n < N_NODES) {
        const int o = loc[n] + bsum[n >> 8];
        off[n] = o; cur[n] = o;
        if (n == 0) off[N_NODES] = N_EDGES;
        b  = min(deg[n], 127);
        rk = atomicAdd(&scnt[b], 1);
    }
    __syncthreads();
    if (t < 128 && scnt[t]) sbase[t] = atomicAdd(cursor + t, scnt[t]);
    __syncthreads();
    if (n < N_NODES) perm[sbase[b] + rk] = n;
}

// scatter edges into dst-sorted order: src id + edge-attr row
__global__ __launch_bounds__(256) void k_pos(
    const int* __restrict__ src, const int* __restrict__ dst,
    const float* __restrict__ ea, int* __restrict__ cur,
    int* __restrict__ src_s, float4* __restrict__ ea_s)
{
    const int e = blockIdx.x * 256 + threadIdx.x;
    if (e < N_EDGES) {
        const float4 a4 = ((const float4*)ea)[e * 2];
        const float4 b4 = ((const float4*)ea)[e * 2 + 1];
        const int p = atomicAdd(cur + dst[e], 1);
        src_s[p] = src[e];
        ea_s[p * 2]     = a4;
        ea_s[p * 2 + 1] = b4;
    }
}

// ---------------------------------------------------------------------------
// K5: rank-1 aggregation + FUSED node-pre epilogue (round-14 EXACT: 104 VGPR,
// 35328 LDS, 4 blocks/CU -- do not touch; caps below 104 spill T[64]).
// ---------------------------------------------------------------------------
__global__ __launch_bounds__(256) void k_agg(
    const float* __restrict__ x, const float4* __restrict__ ea_s,
    const int* __restrict__ src_s, const int* __restrict__ off,
    const int* __restrict__ perm,
    const float* __restrict__ W1, const float* __restrict__ W2,
    const float* __restrict__ ss, const float* __restrict__ root,
    const float* __restrict__ b2, const float* __restrict__ bias,
    float* __restrict__ pre_out, float* __restrict__ bnstats)
{
    __shared__ float4 sW2q[2048];   // 32KB, phys idx = f ^ ((f>>8)&7)
    __shared__ float sroot[256], sb2[256], sbias[16], lacc[32];
    const int tid = threadIdx.x;
    #pragma unroll
    for (int i = 0; i < 8; ++i) {
        const int f = tid + 256 * i;
        sW2q[f ^ ((f >> 8) & 7)] = ((const float4*)W2)[f];
    }
    if (tid < 64) {
        ((float4*)sroot)[tid] = ((const float4*)root)[tid];
        ((float4*)sb2)[tid]   = ((const float4*)b2)[tid];
    }
    if (tid < 16) sbias[tid] = bias[tid];
    if (tid < 32) lacc[tid] = 0.f;
    __syncthreads();

    const int c  = tid & 7;
    const int g  = blockIdx.x * 32 + (tid >> 3);
    const bool valid = (g < N_NODES);
    const int n  = perm[valid ? g : (N_NODES - 1)];

    float w1r[32];                  // W1[j][4c+kk]
    #pragma unroll
    for (int j = 0; j < 8; ++j)
        #pragma unroll
        for (int kk = 0; kk < 4; ++kk)
            w1r[j * 4 + kk] = W1[j * 32 + c * 4 + kk];
    float scr[4], shr[4];
    #pragma unroll
    for (int kk = 0; kk < 4; ++kk) {
        scr[kk] = ss[c * 4 + kk];
        shr[kk] = ss[32 + c * 4 + kk];
    }

    const int o0 = off[n], o1 = off[n + 1];
    const int len = o1 - o0;
    float T[64];
    #pragma unroll
    for (int j = 0; j < 64; ++j) T[j] = 0.f;
    float xs0 = 0.f, xs1 = 0.f;

    // decoupled 2-stage pipeline (round-10 exact)
    float4 ca = make_float4(0,0,0,0), cb = ca;
    float4 cx0 = ca, cx1 = ca, cx2 = ca, cx3 = ca;
    float2 cxs = make_float2(0.f, 0.f);
    float4 pa = ca, pb = ca;
    int    snn = 0;
    if (len > 0) {
        const int s0 = src_s[o0];
        ca = ea_s[(size_t)o0 * 2];
        cb = ea_s[(size_t)o0 * 2 + 1];
        const float4* xp = (const float4*)(x + (size_t)s0 * 16);
        cx0 = xp[0]; cx1 = xp[1]; cx2 = xp[2]; cx3 = xp[3];
        cxs = *(const float2*)(x + (size_t)s0 * 16 + (c << 1));
        pa = ca; pb = cb;
        if (len > 1) {
            snn = src_s[o0 + 1];
            pa = ea_s[(size_t)(o0 + 1) * 2];
            pb = ea_s[(size_t)(o0 + 1) * 2 + 1];
        }
    }
    for (int r = 0; r < len; ++r) {
        float4 nx0 = cx0, nx1 = cx1, nx2 = cx2, nx3 = cx3;
        float2 nxs = cxs;
        float4 qa = pa, qb = pb;
        int sn2 = snn;
        if (r + 1 < len) {
            const float4* xp = (const float4*)(x + (size_t)snn * 16);
            nx0 = xp[0]; nx1 = xp[1]; nx2 = xp[2]; nx3 = xp[3];
            nxs = *(const float2*)(x + (size_t)snn * 16 + (c << 1));
        }
        if (r + 2 < len) {
            sn2 = src_s[o0 + r + 2];
            qa = ea_s[(size_t)(o0 + r + 2) * 2];
            qb = ea_s[(size_t)(o0 + r + 2) * 2 + 1];
        }
        const float ein[8] = {ca.x,ca.y,ca.z,ca.w, cb.x,cb.y,cb.z,cb.w};
        float h[4];
        #pragma unroll
        for (int kk = 0; kk < 4; ++kk) {
            float p = 0.f;
            #pragma unroll
            for (int j = 0; j < 8; ++j) p += ein[j] * w1r[j * 4 + kk];
            h[kk] = fmaxf(p * scr[kk] + shr[kk], 0.f);
        }
        const float xv[16] = {cx0.x,cx0.y,cx0.z,cx0.w, cx1.x,cx1.y,cx1.z,cx1.w,
                              cx2.x,cx2.y,cx2.z,cx2.w, cx3.x,cx3.y,cx3.z,cx3.w};
        #pragma unroll
        for (int kk = 0; kk < 4; ++kk) {
            const float hk = h[kk];
            #pragma unroll
            for (int i = 0; i < 16; ++i) T[kk * 16 + i] += hk * xv[i];
        }
        xs0 += cxs.x;
        xs1 += cxs.y;
        ca = pa; cb = pb;
        cx0 = nx0; cx1 = nx1; cx2 = nx2; cx3 = nx3;
        cxs = nxs;
        pa = qa; pb = qb; snn = sn2;
    }

    // projection (round-10 exact: XOR-swizzled, broadcast across groups)
    float agg[16];
    #pragma unroll
    for (int o = 0; o < 16; ++o) agg[o] = 0.f;
    #pragma unroll
    for (int kk = 0; kk < 4; ++kk) {
        const int fbase = (c * 4 + kk) * 64;
        #pragma unroll
        for (int i = 0; i < 16; ++i) {
            const float tv = T[kk * 16 + i];
            const int f0 = fbase + i * 4;
            const float4 w0 = sW2q[(f0 + 0) ^ c];
            const float4 w1 = sW2q[(f0 + 1) ^ c];
            const float4 w2 = sW2q[(f0 + 2) ^ c];
            const float4 w3 = sW2q[(f0 + 3) ^ c];
            agg[0]+=tv*w0.x; agg[1]+=tv*w0.y; agg[2]+=tv*w0.z; agg[3]+=tv*w0.w;
            agg[4]+=tv*w1.x; agg[5]+=tv*w1.y; agg[6]+=tv*w1.z; agg[7]+=tv*w1.w;
            agg[8]+=tv*w2.x; agg[9]+=tv*w2.y; agg[10]+=tv*w2.z; agg[11]+=tv*w2.w;
            agg[12]+=tv*w3.x; agg[13]+=tv*w3.y; agg[14]+=tv*w3.z; agg[15]+=tv*w3.w;
        }
    }
    #pragma unroll
    for (int m = 1; m < 8; m <<= 1) {
        #pragma unroll
        for (int o = 0; o < 16; ++o) agg[o] += __shfl_xor(agg[o], m);
    }

    // ---------------- fused node-pre epilogue (round-13, verified) --------
    const int gb = (tid & 63) & 56;      // wave-local 8-lane group base
    float xsum[16];
    #pragma unroll
    for (int i = 0; i < 8; ++i) {
        xsum[2 * i]     = __shfl(xs0, gb + i);
        xsum[2 * i + 1] = __shfl(xs1, gb + i);
    }
    const int c0 = c * 2, c1 = c * 2 + 1;
    float p0 = agg[c * 2], p1 = agg[c * 2 + 1];
    #pragma unroll
    for (int i = 0; i < 16; ++i) {
        p0 += xsum[i] * sb2[i * 16 + c0];
        p1 += xsum[i] * sb2[i * 16 + c1];
    }
    const float invd = 1.0f / (float)max(len, 1);
    p0 = p0 * invd + sbias[c0];
    p1 = p1 * invd + sbias[c1];
    const float4* xrp = (const float4*)(x + (size_t)n * 16);
    const float4 r0 = xrp[0], r1 = xrp[1], r2 = xrp[2], r3 = xrp[3];
    const float xn[16] = {r0.x,r0.y,r0.z,r0.w, r1.x,r1.y,r1.z,r1.w,
                          r2.x,r2.y,r2.z,r2.w, r3.x,r3.y,r3.z,r3.w};
    #pragma unroll
    for (int i = 0; i < 16; ++i) {
        p0 += xn[i] * sroot[i * 16 + c0];
        p1 += xn[i] * sroot[i * 16 + c1];
    }
    if (valid) {
        ((float2*)(pre_out + (size_t)n * 16))[c] = make_float2(p0, p1);
    } else { p0 = 0.f; p1 = 0.f; }
    // BN partial stats: reduce across the 8 node-groups in the wave
    float q0 = p0 * p0, q1 = p1 * p1;
    #pragma unroll
    for (int m = 8; m < 64; m <<= 1) {
        p0 += __shfl_xor(p0, m); p1 += __shfl_xor(p1, m);
        q0 += __shfl_xor(q0, m); q1 += __shfl_xor(q1, m);
    }
    if ((tid & 63) < 8) {
        atomicAdd(&lacc[c0], p0);       atomicAdd(&lacc[c1], p1);
        atomicAdd(&lacc[16 + c0], q0);  atomicAdd(&lacc[16 + c1], q1);
    }
    __syncthreads();
    if (tid < 32) atomicAdd(bnstats + tid, lacc[tid]);
}

// ---------------------------------------------------------------------------
// K6: apply node BN + ReLU (conv1): stats are 32 finalized floats
// ---------------------------------------------------------------------------
__global__ __launch_bounds__(256) void k_node_bn(
    const float* __restrict__ pre, const float* __restrict__ bnstats,
    const float* __restrict__ gam, const float* __restrict__ bet,
    float* __restrict__ hout)
{
    __shared__ float sscale[16], sshift[16];
    const int tid = threadIdx.x;
    if (tid < 16) {
        const float mean = bnstats[tid] * (1.0f / N_NODES);
        const float var  = fmaxf(bnstats[16 + tid] * (1.0f / N_NODES) - mean * mean, 0.f);
        const float rs   = rsqrtf(var + EPS);
        const float sc   = gam[tid] * rs;
        sscale[tid] = sc;
        sshift[tid] = bet[tid] - mean * sc;
    }
    __syncthreads();
    const int n = blockIdx.x * 256 + tid;
    if (n >= N_NODES) return;
    const float4* pp = (const float4*)(pre + (size_t)n * 16);
    const float4 p0=pp[0],p1=pp[1],p2=pp[2],p3=pp[3];
    const float pv[16] = {p0.x,p0.y,p0.z,p0.w, p1.x,p1.y,p1.z,p1.w,
                          p2.x,p2.y,p2.z,p2.w, p3.x,p3.y,p3.z,p3.w};
    float h[16];
    #pragma unroll
    for (int o = 0; o < 16; ++o) h[o] = fmaxf(pv[o] * sscale[o] + sshift[o], 0.f);
    float4* hp = (float4*)(hout + (size_t)n * 16);
    hp[0] = make_float4(h[0],h[1],h[2],h[3]);
    hp[1] = make_float4(h[4],h[5],h[6],h[7]);
    hp[2] = make_float4(h[8],h[9],h[10],h[11]);
    hp[3] = make_float4(h[12],h[13],h[14],h[15]);
}

// ---------------------------------------------------------------------------
// K7: per-graph mean pool with BN2+ReLU fused AND head MLP fused (one block
// per graph; head needs only this graph's pooled vector).
// ---------------------------------------------------------------------------
__global__ __launch_bounds__(256) void k_pool_bn(
    const float* __restrict__ pre, const float* __restrict__ bnstats,
    const float* __restrict__ gam, const float* __restrict__ bet,
    const int* __restrict__ start,
    const float* __restrict__ fc1W, const float* __restrict__ fc1b,
    const float* __restrict__ fc2W, const float* __restrict__ fc2b,
    float* __restrict__ out)
{
    __shared__ float sscale[16], sshift[16];
    __shared__ float lds[16][16];
    __shared__ float sp[16], sz[16];
    const int tid = threadIdx.x;
    if (tid < 16) {
        const float mean = bnstats[tid] * (1.0f / N_NODES);
        const float var  = fmaxf(bnstats[16 + tid] * (1.0f / N_NODES) - mean * mean, 0.f);
        const float rs   = rsqrtf(var + EPS);
        const float sc   = gam[tid] * rs;
        sscale[tid] = sc;
        sshift[tid] = bet[tid] - mean * sc;
    }
    __syncthreads();
    const int g = blockIdx.x;
    const int c = tid & 15, rg = tid >> 4;
    const int s = start[g], e = start[g + 1];
    const float sc = sscale[c], sh = sshift[c];
    float acc = 0.f;
    for (int r = s + rg; r < e; r += 16)
        acc += fmaxf(pre[(size_t)r * 16 + c] * sc + sh, 0.f);
    lds[rg][c] = acc;
    __syncthreads();
    if (tid < 16) {
        float sum = 0.f;
        #pragma unroll
        for (int i = 0; i < 16; ++i) sum += lds[i][tid];
        sp[tid] = sum / (float)max(e - s, 1);
    }
    __syncthreads();
    if (tid < 16) {
        float a = fc1b[tid];
        #pragma unroll
        for (int o = 0; o < 16; ++o) a += sp[o] * fc1W[o * 16 + tid];
        sz[tid] = fmaxf(a, 0.f);
    }
    __syncthreads();
    if (tid < NT) {
        float a = fc2b[tid];
        #pragma unroll
        for (int j = 0; j < 16; ++j) a += sz[j] * fc2W[j * 2 + tid];
        out[g * 2 + tid] = a;
    }
}

// ---------------------------------------------------------------------------
extern "C" void kernel_launch(void* const* d_in, const int* in_sizes, int n_in,
                              void* d_out, int out_size, void* d_ws, size_t ws_size,
                              hipStream_t stream)
{
    const float* x    = (const float*)d_in[0];
    const float* ea   = (const float*)d_in[1];
    const float* e1W1 = (const float*)d_in[2];  const float* e1b1 = (const float*)d_in[3];
    const float* e1g  = (const float*)d_in[4];  const float* e1be = (const float*)d_in[5];
    const float* e1W2 = (const float*)d_in[6];  const float* e1b2 = (const float*)d_in[7];
    const float* c1r  = (const float*)d_in[8];  const float* c1b  = (const float*)d_in[9];
    const float* e2W1 = (const float*)d_in[10]; const float* e2b1 = (const float*)d_in[11];
    const float* e2g  = (const float*)d_in[12]; const float* e2be = (const float*)d_in[13];
    const float* e2W2 = (const float*)d_in[14]; const float* e2b2 = (const float*)d_in[15];
    const float* c2r  = (const float*)d_in[16]; const float* c2b  = (const float*)d_in[17];
    const float* bn1g = (const float*)d_in[18]; const float* bn1b = (const float*)d_in[19];
    const float* bn2g = (const float*)d_in[20]; const float* bn2b = (const float*)d_in[21];
    const float* fc1W = (const float*)d_in[22]; const float* fc1b = (const float*)d_in[23];
    const float* fc2W = (const float*)d_in[24]; const float* fc2b = (const float*)d_in[25];
    const int* eidx   = (const int*)d_in[26];
    const int* batch  = (const int*)d_in[27];
    const int* src = eidx;
    const int* dst = eidx + N_EDGES;

    float* ws      = (float*)d_ws;
    float* mom     = ws;                      // 64 (44 used)
    float* bnstats = ws + 64;                 // 64 (32 per conv, zeroed)
    float* ss      = ws + 128;                // 128
    int* hist_i    = (int*)(ws + 256);        // 128 (zeroed)
    int* cursor_i  = (int*)(ws + 384);        // 128
    int* deg_i   = (int*)(ws + 512);          // N (zeroed)
    int* loc_i   = deg_i + N_NODES;           // N
    int* cur_i   = loc_i + N_NODES;           // N
    int* bsum_i  = cur_i + N_NODES;           // 256
    int* start_i = bsum_i + 256;              // 65 (pad 72)
    int* off_i   = start_i + 72;              // N+1 (pad N+8)
    int* perm_i  = off_i + N_NODES + 8;       // N
    int* src_s   = perm_i + N_NODES;          // E
    const size_t fo = 512 + 256 + 72 + 8 + 5 * (size_t)N_NODES + (size_t)N_EDGES;
    float* ea_s  = ws + fo;                        // E*8 (16B aligned)
    float* pre1  = ea_s + (size_t)N_EDGES * 8;     // N*16 (reused as pre2)
    float* h1n   = pre1 + (size_t)N_NODES * 16;    // N*16

    // zero: mom+bnstats+ss+hist+cursor (512 floats) + deg (N ints), contiguous
    hipMemsetAsync(d_ws, 0, (size_t)(512 + N_NODES) * sizeof(float), stream);

    k_moments<<<512, 256, 0, stream>>>(ea, dst, mom, deg_i);
    k_scan1<<<NB_N, 256, 0, stream>>>(deg_i, loc_i, bsum_i, hist_i);
    k_singles<<<1, 256, 0, stream>>>(bsum_i, mom, e1W1, e1b1, e1g, e1be,
                                     e2W1, e2b1, e2g, e2be, ss, batch, start_i,
                                     hist_i, cursor_i);
    k_scan3<<<NB_N, 256, 0, stream>>>(loc_i, bsum_i, deg_i, off_i, cur_i,
                                      cursor_i, perm_i);
    k_pos<<<NB_E, 256, 0, stream>>>(src, dst, ea, cur_i, src_s, (float4*)ea_s);

    k_agg<<<NB_A, 256, 0, stream>>>(x, (const float4*)ea_s, src_s, off_i, perm_i,
                                    e1W1, e1W2, ss, c1r, e1b2, c1b, pre1, bnstats);
    k_node_bn<<<NB_N, 256, 0, stream>>>(pre1, bnstats, bn1g, bn1b, h1n);

    k_agg<<<NB_A, 256, 0, stream>>>(h1n, (const float4*)ea_s, src_s, off_i, perm_i,
                                    e2W1, e2W2, ss + 64, c2r, e2b2, c2b, pre1,
                                    bnstats + 32);
    k_pool_bn<<<NG, 256, 0, stream>>>(pre1, bnstats + 32, bn2g, bn2b, start_i,
                                      fc1W, fc1b, fc2W, fc2b, (float*)d_out);
}